// Round 4
// baseline (140.159 us; speedup 1.0000x reference)
//
#include <hip/hip_runtime.h>
#include <math.h>

#define Bdim 2048
#define Hdim 256
#define KS 32
#define Udim 128
#define OBSD 128
#define PROJD 128
#define H3 768

__device__ __forceinline__ float sigm(float x){ return 1.0f/(1.0f+__expf(-x)); }

// ---------------- Kernel A1: x_in = [tanh(obs@W_obs+b) | tanh(ssum@W_ssum+b)] ----------------
// 16 rows/block, 256 threads: thread -> (src = t>>7, col = t&127), 16 row accumulators.
__global__ __launch_bounds__(256) void kA1(
    const float* __restrict__ obs, const float* __restrict__ ssum,
    const float* __restrict__ W_obs, const float* __restrict__ b_obs,
    const float* __restrict__ W_ssum, const float* __restrict__ b_ssum,
    float* __restrict__ xin)
{
    __shared__ float s_in[2][16][128];
    const int t = threadIdx.x;
    const int r0 = blockIdx.x * 16;

    // stage 16 rows of obs and ssum
    #pragma unroll
    for (int u=0;u<2;u++){
        int idx = t + 256*u;            // 0..511
        int r = idx >> 5, c4 = (idx & 31) << 2;
        float4 v = *(const float4*)(obs + (size_t)(r0+r)*OBSD + c4);
        s_in[0][r][c4+0]=v.x; s_in[0][r][c4+1]=v.y; s_in[0][r][c4+2]=v.z; s_in[0][r][c4+3]=v.w;
        v = *(const float4*)(ssum + (size_t)(r0+r)*OBSD + c4);
        s_in[1][r][c4+0]=v.x; s_in[1][r][c4+1]=v.y; s_in[1][r][c4+2]=v.z; s_in[1][r][c4+3]=v.w;
    }
    __syncthreads();

    const int col = t & 127;
    const int src = t >> 7;
    const float* Wp = src ? W_ssum : W_obs;
    const float bb = src ? b_ssum[col] : b_obs[col];

    float acc[16];
    #pragma unroll
    for (int r=0;r<16;r++) acc[r] = 0.f;

    for (int i=0;i<128;i++){
        float w = Wp[i*PROJD + col];
        #pragma unroll
        for (int r=0;r<16;r++) acc[r] = fmaf(s_in[src][r][i], w, acc[r]);
    }
    #pragma unroll
    for (int r=0;r<16;r++)
        xin[(size_t)(r0+r)*256 + t] = tanhf(acc[r] + bb);
}

// ---------------- Kernel G2: g(2048x1024) = [x_in|h_prev](2048x512) @ [Wi;Wh]'(512x1024) ----
// cols [0:256)=ir+hr, [256:512)=iz+hz, [512:768)=inn (K=x half), [768:1024)=hn (K=h half)
// tile 128x64, 512 threads, thread = 4x4, K-chunk 16, double-buffered LDS.
__global__ __launch_bounds__(512) void kG2(
    const float* __restrict__ xin, const float* __restrict__ hp,
    const float* __restrict__ Wi, const float* __restrict__ Wh,
    float* __restrict__ g)
{
    __shared__ float Xt[2][16][132];   // [buf][kk][row], transposed, padded
    __shared__ float Wt[2][16][64];    // [buf][kk][col]

    const int t = threadIdx.x;
    const int bx = blockIdx.x >> 4;        // row block 0..15
    const int by = blockIdx.x & 15;        // col block 0..15
    const int r0 = bx * 128;
    const int c0 = by * 64;

    const int kbeg = (c0 >= 768) ? 256 : 0;
    const int kend = (c0 >= 512 && c0 < 768) ? 256 : 512;
    const int nck  = (kend - kbeg) >> 4;

    // staging map: X tile 128 rows x 16 k -> 512 float4
    const int sr  = t >> 2;                // 0..127
    const int sk4 = (t & 3) << 2;          // 0,4,8,12
    const size_t xbase = (size_t)(r0 + sr) * 256 + sk4;
    // W staging: threads 0..255, 16 rows x 64 cols -> 256 float4
    const int wk  = t >> 4;                // 0..15 (valid for t<256)
    const int wc4 = (t & 15) << 2;
    const int cW  = (c0 < 512) ? c0 : (c0 - 256);   // Wh column base

    // compute map: thread = rows 4*(t&31).., cols 4*(t>>5)..
    const int rowA = (t & 31) << 2;
    const int colA = (t >> 5) << 2;

    float acc[4][4] = {{0.f}};
    float4 xr, wr;

    // ---- load chunk 0 into regs ----
    {
        const int k0 = kbeg;
        const float* xs = (k0 < 256) ? (xin + xbase + k0) : (hp + xbase + (k0 - 256));
        xr = *(const float4*)xs;
        if (t < 256){
            const int k = k0 + wk;
            const float* wsrc = (k < 256) ? (Wi + (size_t)k*H3 + c0 + wc4)
                                          : (Wh + (size_t)(k-256)*H3 + cW + wc4);
            wr = *(const float4*)wsrc;
        }
    }
    Xt[0][sk4+0][sr] = xr.x; Xt[0][sk4+1][sr] = xr.y;
    Xt[0][sk4+2][sr] = xr.z; Xt[0][sk4+3][sr] = xr.w;
    if (t < 256) *(float4*)&Wt[0][wk][wc4] = wr;
    __syncthreads();

    for (int ck = 0; ck < nck; ck++){
        const int cur = ck & 1;
        const bool more = (ck + 1 < nck);
        if (more){
            const int k0 = kbeg + ((ck + 1) << 4);
            const float* xs = (k0 < 256) ? (xin + xbase + k0) : (hp + xbase + (k0 - 256));
            xr = *(const float4*)xs;
            if (t < 256){
                const int k = k0 + wk;
                const float* wsrc = (k < 256) ? (Wi + (size_t)k*H3 + c0 + wc4)
                                              : (Wh + (size_t)(k-256)*H3 + cW + wc4);
                wr = *(const float4*)wsrc;
            }
        }
        #pragma unroll
        for (int kk = 0; kk < 16; kk++){
            float4 a4 = *(const float4*)&Xt[cur][kk][rowA];
            float4 b4 = *(const float4*)&Wt[cur][kk][colA];
            float av[4] = {a4.x, a4.y, a4.z, a4.w};
            float bv[4] = {b4.x, b4.y, b4.z, b4.w};
            #pragma unroll
            for (int i=0;i<4;i++)
                #pragma unroll
                for (int j=0;j<4;j++)
                    acc[i][j] = fmaf(av[i], bv[j], acc[i][j]);
        }
        if (more){
            const int nxt = cur ^ 1;
            Xt[nxt][sk4+0][sr] = xr.x; Xt[nxt][sk4+1][sr] = xr.y;
            Xt[nxt][sk4+2][sr] = xr.z; Xt[nxt][sk4+3][sr] = xr.w;
            if (t < 256) *(float4*)&Wt[nxt][wk][wc4] = wr;
            __syncthreads();
        }
    }

    #pragma unroll
    for (int i=0;i<4;i++){
        float4 o = make_float4(acc[i][0], acc[i][1], acc[i][2], acc[i][3]);
        *(float4*)&g[(size_t)(r0 + rowA + i)*1024 + c0 + colA] = o;
    }
}

// ---------------- Kernel A3: GRU combine + norm + gate ----------------
__global__ __launch_bounds__(256) void kA3(
    const float* __restrict__ g, const float* __restrict__ h_prev,
    const float* __restrict__ bi, const float* __restrict__ bhn,
    const float* __restrict__ W_gate, const float* __restrict__ b_gate,
    float* __restrict__ out_h, float* __restrict__ ws_qn, float* __restrict__ ws_wstr)
{
    __shared__ float redA[8][4], redB[8][4];
    __shared__ float s_inv[8];
    const int t = threadIdx.x;
    const int r0 = blockIdx.x * 8;

    const float bir = bi[t], biz = bi[t+256], bin_ = bi[t+512];
    const float bh = bhn[t];
    const float wg = W_gate[t];
    const int lane = t & 63, wid = t >> 6;

    float hv[8];
    #pragma unroll
    for (int r=0;r<8;r++){
        const size_t gb = (size_t)(r0+r)*1024;
        float gr = g[gb + t];
        float gz = g[gb + 256 + t];
        float gni = g[gb + 512 + t];
        float gnh = g[gb + 768 + t];
        float hp = h_prev[(size_t)(r0+r)*Hdim + t];
        float rr = sigm(gr + bir);
        float zz = sigm(gz + biz);
        float nn = tanhf(gni + bin_ + rr*(gnh + bh));
        hv[r] = (1.0f - zz)*nn + zz*hp;
    }

    #pragma unroll
    for (int r=0;r<8;r++){
        float a = hv[r]*hv[r];
        float b2 = hv[r]*wg;
        #pragma unroll
        for (int off=32; off>=1; off>>=1){
            a  += __shfl_down(a, off);
            b2 += __shfl_down(b2, off);
        }
        if (lane==0){ redA[r][wid]=a; redB[r][wid]=b2; }
    }
    __syncthreads();
    if (t < 8){
        float ss = redA[t][0]+redA[t][1]+redA[t][2]+redA[t][3];
        float gd = redB[t][0]+redB[t][1]+redB[t][2]+redB[t][3];
        s_inv[t] = 1.0f/(sqrtf(ss) + 1e-6f);
        ws_wstr[r0+t] = sigm(gd + b_gate[0]);
    }
    __syncthreads();
    #pragma unroll
    for (int r=0;r<8;r++){
        out_h[(size_t)(r0+r)*Hdim + t] = hv[r];
        ws_qn[(size_t)(r0+r)*Hdim + t] = hv[r]*s_inv[r];
    }
}

// ---------------- Kernel B: episodic memory read/write ----------------
__global__ __launch_bounds__(256) void kB(
    const float* __restrict__ keys, const float* __restrict__ vals,
    const float* __restrict__ age, const float* __restrict__ strength,
    const float* __restrict__ h_t, const float* __restrict__ ws_qn,
    const float* __restrict__ ws_wstr,
    float* __restrict__ keys_new, float* __restrict__ vals_new,
    float* __restrict__ age_new, float* __restrict__ str_new,
    float* __restrict__ ws_ro)
{
    __shared__ float s_sim[KS], s_age[KS], s_str[KS], s_logit[KS], s_wl[KS];
    __shared__ float4 s_ro[4][64];

    const int b = blockIdx.x;
    const int t = threadIdx.x, lane = t & 63, wid = t >> 6;

    if (t < KS){ s_age[t] = age[b*KS+t]; s_str[t] = strength[b*KS+t]; }

    const float4 q4 = ((const float4*)(ws_qn + (size_t)b*Hdim))[lane];
    const float4 h4 = ((const float4*)(h_t + (size_t)b*Hdim))[lane];
    const float wstr = ws_wstr[b];

    const float4* K4 = (const float4*)(keys + (size_t)b*KS*Hdim);
    const float4* V4 = (const float4*)(vals + (size_t)b*KS*Hdim);
    float4 kreg[8], vreg[8];
    #pragma unroll
    for (int s=0;s<8;s++){
        int k = wid*8 + s;
        kreg[s] = K4[k*64 + lane];
        vreg[s] = V4[k*64 + lane];
        float d  = kreg[s].x*q4.x + kreg[s].y*q4.y + kreg[s].z*q4.z + kreg[s].w*q4.w;
        float sq = kreg[s].x*kreg[s].x + kreg[s].y*kreg[s].y + kreg[s].z*kreg[s].z + kreg[s].w*kreg[s].w;
        #pragma unroll
        for (int off=32; off>=1; off>>=1){
            d  += __shfl_down(d, off);
            sq += __shfl_down(sq, off);
        }
        if (lane==0) s_sim[k] = d / (sqrtf(sq) + 1e-6f);
    }
    __syncthreads();

    if (t < KS){
        float sim = s_sim[t], st = s_str[t], ag = s_age[t];
        float cl = fminf(fmaxf(st, 0.001f), 1.0f);
        s_logit[t] = sim + 0.5f*logf(cl) - 0.02f*ag;
        s_wl[t] = 50.0f*sim + 0.05f*log1pf(ag) - 0.5f*st;
    }
    __syncthreads();

    float lmax = -1e30f, wmax = -1e30f; int kst = 0;
    for (int k=0;k<KS;k++){
        lmax = fmaxf(lmax, s_logit[k]);
        float wl = s_wl[k];
        if (wl > wmax){ wmax = wl; kst = k; }
    }
    float esum = 0.f;
    for (int k=0;k<KS;k++) esum += __expf(s_logit[k]-lmax);
    const float inv_esum = 1.0f/esum;

    float4 ro = make_float4(0.f,0.f,0.f,0.f);
    float4* KN4 = (float4*)(keys_new + (size_t)b*KS*Hdim);
    float4* VN4 = (float4*)(vals_new + (size_t)b*KS*Hdim);
    #pragma unroll
    for (int s=0;s<8;s++){
        int k = wid*8 + s;
        float wr = __expf(s_logit[k]-lmax)*inv_esum;
        ro.x = fmaf(wr, vreg[s].x, ro.x);
        ro.y = fmaf(wr, vreg[s].y, ro.y);
        ro.z = fmaf(wr, vreg[s].z, ro.z);
        ro.w = fmaf(wr, vreg[s].w, ro.w);
        float rate = (k==kst) ? 0.5f*wstr : 0.0f;
        float om = 1.0f - rate;
        float4 kn, vn;
        kn.x = om*kreg[s].x + rate*q4.x;
        kn.y = om*kreg[s].y + rate*q4.y;
        kn.z = om*kreg[s].z + rate*q4.z;
        kn.w = om*kreg[s].w + rate*q4.w;
        vn.x = om*vreg[s].x + rate*h4.x;
        vn.y = om*vreg[s].y + rate*h4.y;
        vn.z = om*vreg[s].z + rate*h4.z;
        vn.w = om*vreg[s].w + rate*h4.w;
        KN4[k*64+lane] = kn;
        VN4[k*64+lane] = vn;
    }
    s_ro[wid][lane] = ro;

    if (t < KS){
        float hard = (t==kst) ? 1.0f : 0.0f;
        age_new[b*KS+t] = (s_age[t]+1.0f)*(1.0f-hard);
        float sd = s_str[t]*0.995f;
        float sn = sd + hard*wstr*(1.0f-sd);
        str_new[b*KS+t] = fminf(fmaxf(sn,0.f),1.f);
    }
    __syncthreads();
    if (t < 64){
        float4 a = s_ro[0][t], bb = s_ro[1][t], c = s_ro[2][t], d = s_ro[3][t];
        float4 r;
        r.x = a.x+bb.x+c.x+d.x;
        r.y = a.y+bb.y+c.y+d.y;
        r.z = a.z+bb.z+c.z+d.z;
        r.w = a.w+bb.w+c.w+d.w;
        ((float4*)(ws_ro + (size_t)b*Hdim))[t] = r;
    }
}

// ---------------- Kernel C: output head ----------------
__global__ __launch_bounds__(256) void kC(
    const float* __restrict__ h_t, const float* __restrict__ ws_ro,
    const float* __restrict__ u_int_prev, const int* __restrict__ step_in_macro,
    const float* __restrict__ W_mean, const float* __restrict__ b_mean,
    const float* __restrict__ W_beta, const float* __restrict__ b_beta,
    const float* __restrict__ W_sw, const float* __restrict__ b_sw,
    float* __restrict__ out_uprop, float* __restrict__ out_switch,
    float* __restrict__ out_uint, float* __restrict__ out_beta, float* __restrict__ out_swp)
{
    __shared__ float s_ctx[8][512];
    __shared__ float redb[8][4], reds[8][4];
    __shared__ float s_beff[8];
    const int t = threadIdx.x;
    const int r0 = blockIdx.x * 8;

    {
        const float4* hh = (const float4*)(h_t + (size_t)r0*Hdim);
        const float4* rr4 = (const float4*)(ws_ro + (size_t)r0*Hdim);
        #pragma unroll
        for (int u=0;u<2;u++){
            int idx = t + u*256;
            int r = idx >> 6, c = (idx & 63)*4;
            float4 v = hh[idx];
            s_ctx[r][c+0]=v.x; s_ctx[r][c+1]=v.y; s_ctx[r][c+2]=v.z; s_ctx[r][c+3]=v.w;
            v = rr4[idx];
            s_ctx[r][256+c+0]=v.x; s_ctx[r][256+c+1]=v.y; s_ctx[r][256+c+2]=v.z; s_ctx[r][256+c+3]=v.w;
        }
    }
    __syncthreads();

    const int c = t & 127;
    const int rbase = (t >> 7) * 4;
    float acc[4] = {0,0,0,0};
    for (int i=0;i<512;i++){
        float w = W_mean[i*Udim + c];
        #pragma unroll
        for (int j=0;j<4;j++) acc[j] = fmaf(s_ctx[rbase+j][i], w, acc[j]);
    }

    float pb[8]={0,0,0,0,0,0,0,0}, ps[8]={0,0,0,0,0,0,0,0};
    for (int i=t; i<512; i+=256){
        float wb = W_beta[i], wsw = W_sw[i];
        #pragma unroll
        for (int r=0;r<8;r++){
            pb[r] = fmaf(s_ctx[r][i], wb, pb[r]);
            ps[r] = fmaf(s_ctx[r][i], wsw, ps[r]);
        }
    }
    const int lane = t & 63, wid = t >> 6;
    #pragma unroll
    for (int r=0;r<8;r++){
        float a = pb[r], b2 = ps[r];
        #pragma unroll
        for (int off=32; off>=1; off>>=1){
            a  += __shfl_down(a, off);
            b2 += __shfl_down(b2, off);
        }
        if (lane==0){ redb[r][wid]=a; reds[r][wid]=b2; }
    }
    __syncthreads();
    if (t < 8){
        float db  = redb[t][0]+redb[t][1]+redb[t][2]+redb[t][3] + b_beta[0];
        float dsw = reds[t][0]+reds[t][1]+reds[t][2]+reds[t][3] + b_sw[0];
        float beta = 0.05f + 0.945f*sigm(db);
        float swp = sigm(dsw);
        float swf = (swp > 0.5f) ? 1.0f : 0.0f;
        if (step_in_macro[r0+t] == 0) swf = 1.0f;
        out_beta[r0+t] = beta;
        out_swp[r0+t] = swp;
        out_switch[r0+t] = swf;
        s_beff[t] = beta*(1.0f - swf);
    }
    __syncthreads();
    #pragma unroll
    for (int j=0;j<4;j++){
        int r = rbase + j;
        float mean = acc[j] + b_mean[c];
        size_t o = (size_t)(r0+r)*Udim + c;
        out_uprop[o] = mean;
        float be = s_beff[r];
        out_uint[o] = be*u_int_prev[o] + (1.0f-be)*mean;
    }
}

extern "C" void kernel_launch(void* const* d_in, const int* in_sizes, int n_in,
                              void* d_out, int out_size, void* d_ws, size_t ws_size,
                              hipStream_t stream)
{
    const float* h_prev   = (const float*)d_in[0];
    const float* keys     = (const float*)d_in[1];
    const float* vals     = (const float*)d_in[2];
    const float* age      = (const float*)d_in[3];
    const float* strength = (const float*)d_in[4];
    const float* obs      = (const float*)d_in[5];
    const float* ssum     = (const float*)d_in[6];
    const float* u_int_prev = (const float*)d_in[7];
    const int*   step     = (const int*)d_in[8];
    const float* W_obs    = (const float*)d_in[9];
    const float* b_obs    = (const float*)d_in[10];
    const float* W_ssum   = (const float*)d_in[11];
    const float* b_ssum   = (const float*)d_in[12];
    const float* Wi       = (const float*)d_in[13];
    const float* bi       = (const float*)d_in[14];
    const float* Wh       = (const float*)d_in[15];
    const float* bhn      = (const float*)d_in[16];
    const float* W_gate   = (const float*)d_in[17];
    const float* b_gate   = (const float*)d_in[18];
    const float* W_mean   = (const float*)d_in[19];
    const float* b_mean   = (const float*)d_in[20];
    const float* W_beta   = (const float*)d_in[22];
    const float* b_beta   = (const float*)d_in[23];
    const float* W_sw     = (const float*)d_in[24];
    const float* b_sw     = (const float*)d_in[25];

    float* out = (float*)d_out;
    float* out_h    = out;                       // 2048*256
    float* out_kn   = out_h   + 524288;          // 2048*32*256
    float* out_vn   = out_kn  + 16777216;
    float* out_age  = out_vn  + 16777216;        // 2048*32
    float* out_str  = out_age + 65536;
    float* out_up   = out_str + 65536;           // 2048*128
    float* out_sw   = out_up  + 262144;          // 2048
    float* out_ui   = out_sw  + 2048;            // 2048*128
    float* out_beta = out_ui  + 262144;          // 2048
    float* out_swp  = out_beta+ 2048;            // 2048

    float* ws = (float*)d_ws;
    float* ws_qn   = ws;                         // B*H
    float* ws_ro   = ws + Bdim*Hdim;             // B*H
    float* ws_wstr = ws + 2*Bdim*Hdim;           // B

    // scratch reusing output regions (consumed before kB overwrites them)
    float* ws_xin = out_vn;                      // B*256 floats, overwritten by kB later
    float* ws_g   = out_kn;                      // B*1024 floats, overwritten by kB later

    kA1<<<Bdim/16, 256, 0, stream>>>(obs, ssum, W_obs, b_obs, W_ssum, b_ssum, ws_xin);
    kG2<<<256, 512, 0, stream>>>(ws_xin, h_prev, Wi, Wh, ws_g);
    kA3<<<Bdim/8, 256, 0, stream>>>(ws_g, h_prev, bi, bhn, W_gate, b_gate,
                                    out_h, ws_qn, ws_wstr);
    kB<<<Bdim, 256, 0, stream>>>(keys, vals, age, strength, out_h, ws_qn, ws_wstr,
                                 out_kn, out_vn, out_age, out_str, ws_ro);
    kC<<<Bdim/8, 256, 0, stream>>>(out_h, ws_ro, u_int_prev, step, W_mean, b_mean,
                                   W_beta, b_beta, W_sw, b_sw,
                                   out_up, out_sw, out_ui, out_beta, out_swp);
}

// Round 5
// 126.927 us; speedup vs baseline: 1.1043x; 1.1043x over previous
//
#include <hip/hip_runtime.h>
#include <math.h>

#define Bdim 2048
#define Hdim 256
#define KS 32
#define Udim 128
#define OBSD 128
#define PROJD 128
#define H3 768

__device__ __forceinline__ float sigm(float x){ return 1.0f/(1.0f+__expf(-x)); }

typedef float __attribute__((ext_vector_type(4))) f32x4;

__device__ __forceinline__ float4 ntload4(const float* p){
    f32x4 v = __builtin_nontemporal_load((const f32x4*)p);
    return make_float4(v.x, v.y, v.z, v.w);
}
__device__ __forceinline__ void ntstore4(float* p, float4 q){
    f32x4 v = {q.x, q.y, q.z, q.w};
    __builtin_nontemporal_store(v, (f32x4*)p);
}

// ---------------- Kernel A1: x_in = [tanh(obs@W_obs+b) | tanh(ssum@W_ssum+b)] ----------------
// 8 rows/block, 256 blocks (1/CU... with 2 waves of work each), thread -> (src=t>>7, col=t&127).
__global__ __launch_bounds__(256) void kA1(
    const float* __restrict__ obs, const float* __restrict__ ssum,
    const float* __restrict__ W_obs, const float* __restrict__ b_obs,
    const float* __restrict__ W_ssum, const float* __restrict__ b_ssum,
    float* __restrict__ xin)
{
    __shared__ float s_in[2][8][128];
    const int t = threadIdx.x;
    const int r0 = blockIdx.x * 8;

    {
        int r = t >> 5, c4 = (t & 31) << 2;
        float4 v = *(const float4*)(obs + (size_t)(r0+r)*OBSD + c4);
        s_in[0][r][c4+0]=v.x; s_in[0][r][c4+1]=v.y; s_in[0][r][c4+2]=v.z; s_in[0][r][c4+3]=v.w;
        v = *(const float4*)(ssum + (size_t)(r0+r)*OBSD + c4);
        s_in[1][r][c4+0]=v.x; s_in[1][r][c4+1]=v.y; s_in[1][r][c4+2]=v.z; s_in[1][r][c4+3]=v.w;
    }
    __syncthreads();

    const int col = t & 127;
    const int src = t >> 7;
    const float* Wp = src ? W_ssum : W_obs;
    const float bb = src ? b_ssum[col] : b_obs[col];

    float acc[8] = {0,0,0,0,0,0,0,0};
    for (int i=0;i<128;i++){
        float w = Wp[i*PROJD + col];
        #pragma unroll
        for (int r=0;r<8;r++) acc[r] = fmaf(s_in[src][r][i], w, acc[r]);
    }
    #pragma unroll
    for (int r=0;r<8;r++)
        xin[(size_t)(r0+r)*256 + t] = tanhf(acc[r] + bb);
}

// ---------------- Kernel G2: g(2048x1024) = [x_in|h_prev](2048x512) @ [Wi;Wh]'(512x1024) ----
// 64x64 tiles, 256 threads (thread=4x4), 512 blocks = 2 blocks/CU, K-chunk 16 double-buffered.
__global__ __launch_bounds__(256) void kG2(
    const float* __restrict__ xin, const float* __restrict__ hp,
    const float* __restrict__ Wi, const float* __restrict__ Wh,
    float* __restrict__ g)
{
    __shared__ float Xt[2][16][68];    // [buf][kk][row], transposed, padded
    __shared__ float Wt[2][16][64];

    const int t = threadIdx.x;
    const int bx = blockIdx.x >> 4;        // 0..31
    const int by = blockIdx.x & 15;        // 0..15
    const int r0 = bx * 64;
    const int c0 = by * 64;

    const int kbeg = (c0 >= 768) ? 256 : 0;
    const int kend = (c0 >= 512 && c0 < 768) ? 256 : 512;
    const int nck  = (kend - kbeg) >> 4;

    const int sr  = t >> 2;                // 0..63
    const int sk4 = (t & 3) << 2;          // 0,4,8,12
    const size_t xbase = (size_t)(r0 + sr) * 256 + sk4;
    const int wk  = t >> 4;                // 0..15
    const int wc4 = (t & 15) << 2;
    const int cW  = (c0 < 512) ? c0 : (c0 - 256);

    const int rowA = (t & 15) << 2;
    const int colA = (t >> 4) << 2;

    float acc[4][4] = {{0.f}};
    float4 xr, wr;

    {
        const int k0 = kbeg;
        const float* xs = (k0 < 256) ? (xin + xbase + k0) : (hp + xbase + (k0 - 256));
        xr = *(const float4*)xs;
        const int k = k0 + wk;
        const float* wsrc = (k < 256) ? (Wi + (size_t)k*H3 + c0 + wc4)
                                      : (Wh + (size_t)(k-256)*H3 + cW + wc4);
        wr = *(const float4*)wsrc;
    }
    Xt[0][sk4+0][sr] = xr.x; Xt[0][sk4+1][sr] = xr.y;
    Xt[0][sk4+2][sr] = xr.z; Xt[0][sk4+3][sr] = xr.w;
    *(float4*)&Wt[0][wk][wc4] = wr;
    __syncthreads();

    for (int ck = 0; ck < nck; ck++){
        const int cur = ck & 1;
        const bool more = (ck + 1 < nck);
        if (more){
            const int k0 = kbeg + ((ck + 1) << 4);
            const float* xs = (k0 < 256) ? (xin + xbase + k0) : (hp + xbase + (k0 - 256));
            xr = *(const float4*)xs;
            const int k = k0 + wk;
            const float* wsrc = (k < 256) ? (Wi + (size_t)k*H3 + c0 + wc4)
                                          : (Wh + (size_t)(k-256)*H3 + cW + wc4);
            wr = *(const float4*)wsrc;
        }
        #pragma unroll
        for (int kk = 0; kk < 16; kk++){
            float4 a4 = *(const float4*)&Xt[cur][kk][rowA];
            float4 b4 = *(const float4*)&Wt[cur][kk][colA];
            float av[4] = {a4.x, a4.y, a4.z, a4.w};
            float bv[4] = {b4.x, b4.y, b4.z, b4.w};
            #pragma unroll
            for (int i=0;i<4;i++)
                #pragma unroll
                for (int j=0;j<4;j++)
                    acc[i][j] = fmaf(av[i], bv[j], acc[i][j]);
        }
        if (more){
            const int nxt = cur ^ 1;
            Xt[nxt][sk4+0][sr] = xr.x; Xt[nxt][sk4+1][sr] = xr.y;
            Xt[nxt][sk4+2][sr] = xr.z; Xt[nxt][sk4+3][sr] = xr.w;
            *(float4*)&Wt[nxt][wk][wc4] = wr;
            __syncthreads();
        }
    }

    #pragma unroll
    for (int i=0;i<4;i++){
        float4 o = make_float4(acc[i][0], acc[i][1], acc[i][2], acc[i][3]);
        *(float4*)&g[(size_t)(r0 + rowA + i)*1024 + c0 + colA] = o;
    }
}

// ---------------- Kernel A3: GRU combine + norm + gate ----------------
__global__ __launch_bounds__(256) void kA3(
    const float* __restrict__ g, const float* __restrict__ h_prev,
    const float* __restrict__ bi, const float* __restrict__ bhn,
    const float* __restrict__ W_gate, const float* __restrict__ b_gate,
    float* __restrict__ out_h, float* __restrict__ ws_qn, float* __restrict__ ws_wstr)
{
    __shared__ float redA[8][4], redB[8][4];
    __shared__ float s_inv[8];
    const int t = threadIdx.x;
    const int r0 = blockIdx.x * 8;

    const float bir = bi[t], biz = bi[t+256], bin_ = bi[t+512];
    const float bh = bhn[t];
    const float wg = W_gate[t];
    const int lane = t & 63, wid = t >> 6;

    float hv[8];
    #pragma unroll
    for (int r=0;r<8;r++){
        const size_t gb = (size_t)(r0+r)*1024;
        float gr = g[gb + t];
        float gz = g[gb + 256 + t];
        float gni = g[gb + 512 + t];
        float gnh = g[gb + 768 + t];
        float hp = h_prev[(size_t)(r0+r)*Hdim + t];
        float rr = sigm(gr + bir);
        float zz = sigm(gz + biz);
        float nn = tanhf(gni + bin_ + rr*(gnh + bh));
        hv[r] = (1.0f - zz)*nn + zz*hp;
    }

    #pragma unroll
    for (int r=0;r<8;r++){
        float a = hv[r]*hv[r];
        float b2 = hv[r]*wg;
        #pragma unroll
        for (int off=32; off>=1; off>>=1){
            a  += __shfl_down(a, off);
            b2 += __shfl_down(b2, off);
        }
        if (lane==0){ redA[r][wid]=a; redB[r][wid]=b2; }
    }
    __syncthreads();
    if (t < 8){
        float ss = redA[t][0]+redA[t][1]+redA[t][2]+redA[t][3];
        float gd = redB[t][0]+redB[t][1]+redB[t][2]+redB[t][3];
        s_inv[t] = 1.0f/(sqrtf(ss) + 1e-6f);
        ws_wstr[r0+t] = sigm(gd + b_gate[0]);
    }
    __syncthreads();
    #pragma unroll
    for (int r=0;r<8;r++){
        out_h[(size_t)(r0+r)*Hdim + t] = hv[r];
        ws_qn[(size_t)(r0+r)*Hdim + t] = hv[r]*s_inv[r];
    }
}

// ---------------- Kernel B: episodic memory read/write ----------------
// Reduce-scatter butterfly: 16 partials (8 slot-dots + 8 slot-norms) over 64 lanes
// in 18 shuffles instead of 8x2x6=96. Softmax/argmax on lanes 0..31 via 5-step shuffles.
__global__ __launch_bounds__(256) void kB(
    const float* __restrict__ keys, const float* __restrict__ vals,
    const float* __restrict__ age, const float* __restrict__ strength,
    const float* __restrict__ h_t, const float* __restrict__ ws_qn,
    const float* __restrict__ ws_wstr,
    float* __restrict__ keys_new, float* __restrict__ vals_new,
    float* __restrict__ age_new, float* __restrict__ str_new,
    float* __restrict__ ws_ro)
{
    __shared__ float s_sim[KS], s_wr[KS], s_rate[KS];
    __shared__ float4 s_ro[4][64];

    const int b = blockIdx.x;
    const int t = threadIdx.x, lane = t & 63, wid = t >> 6;

    float ag = 0.f, st = 0.f, wstr = 0.f;
    if (t < KS){
        ag = age[b*KS+t];
        st = strength[b*KS+t];
        wstr = ws_wstr[b];
    }

    const float4 q4 = ((const float4*)(ws_qn + (size_t)b*Hdim))[lane];
    const float4 h4 = ((const float4*)(h_t  + (size_t)b*Hdim))[lane];

    const float* Kb = keys + (size_t)b*KS*Hdim;
    const float* Vb = vals + (size_t)b*KS*Hdim;
    float4 kreg[8], vreg[8];
    float v[16];
    #pragma unroll
    for (int s=0;s<8;s++){
        const int k = wid*8 + s;
        kreg[s] = ntload4(Kb + k*Hdim + lane*4);
        vreg[s] = ntload4(Vb + k*Hdim + lane*4);
        v[2*s]   = kreg[s].x*q4.x + kreg[s].y*q4.y + kreg[s].z*q4.z + kreg[s].w*q4.w;
        v[2*s+1] = kreg[s].x*kreg[s].x + kreg[s].y*kreg[s].y + kreg[s].z*kreg[s].z + kreg[s].w*kreg[s].w;
    }

    // ---- reduce-scatter butterfly over 64 lanes ----
    {
        const bool hb5 = (lane & 32) != 0;
        #pragma unroll
        for (int i=0;i<8;i++){
            float send = hb5 ? v[i] : v[i+8];
            float recv = __shfl_xor(send, 32);
            v[i] = (hb5 ? v[i+8] : v[i]) + recv;
        }
        const bool hb4 = (lane & 16) != 0;
        #pragma unroll
        for (int i=0;i<4;i++){
            float send = hb4 ? v[i] : v[i+4];
            float recv = __shfl_xor(send, 16);
            v[i] = (hb4 ? v[i+4] : v[i]) + recv;
        }
        const bool hb3 = (lane & 8) != 0;
        #pragma unroll
        for (int i=0;i<2;i++){
            float send = hb3 ? v[i] : v[i+2];
            float recv = __shfl_xor(send, 8);
            v[i] = (hb3 ? v[i+2] : v[i]) + recv;
        }
        const bool hb2 = (lane & 4) != 0;
        {
            float send = hb2 ? v[0] : v[1];
            float recv = __shfl_xor(send, 4);
            v[0] = (hb2 ? v[1] : v[0]) + recv;
        }
        float r0 = v[0];
        r0 += __shfl_xor(r0, 2);
        r0 += __shfl_xor(r0, 1);
        // lane holds: slot s = lane>>3 (within wave's 8), quantity = (lane&4)? norm : dot
        float other = __shfl_xor(r0, 4);
        if ((lane & 7) == 0){
            s_sim[wid*8 + (lane>>3)] = r0 / (sqrtf(other) + 1e-6f);
        }
    }
    __syncthreads();

    // ---- softmax + argmax on lanes 0..31 of wave 0 ----
    if (t < KS){
        float sim = s_sim[t];
        float cl = fminf(fmaxf(st, 0.001f), 1.0f);
        float logit = sim + 0.5f*logf(cl) - 0.02f*ag;
        float wl = 50.0f*sim + 0.05f*log1pf(ag) - 0.5f*st;

        float lmax = logit;
        #pragma unroll
        for (int off=16; off>=1; off>>=1)
            lmax = fmaxf(lmax, __shfl_xor(lmax, off));
        float e = __expf(logit - lmax);
        float es = e;
        #pragma unroll
        for (int off=16; off>=1; off>>=1)
            es += __shfl_xor(es, off);

        float wm = wl; int ki = t;
        #pragma unroll
        for (int off=16; off>=1; off>>=1){
            float ow = __shfl_xor(wm, off);
            int   ok = __shfl_xor(ki, off);
            if (ow > wm || (ow == wm && ok < ki)){ wm = ow; ki = ok; }
        }

        s_wr[t] = e / es;
        float hard = (t == ki) ? 1.0f : 0.0f;
        s_rate[t] = hard * 0.5f * wstr;
        age_new[b*KS+t] = (ag + 1.0f)*(1.0f - hard);
        float sd = st*0.995f;
        float sn = sd + hard*wstr*(1.0f - sd);
        str_new[b*KS+t] = fminf(fmaxf(sn,0.f),1.f);
    }
    __syncthreads();

    // ---- streaming update + read_out ----
    float4 ro = make_float4(0.f,0.f,0.f,0.f);
    float* KNb = keys_new + (size_t)b*KS*Hdim;
    float* VNb = vals_new + (size_t)b*KS*Hdim;
    #pragma unroll
    for (int s=0;s<8;s++){
        const int k = wid*8 + s;
        const float wr = s_wr[k];
        const float rate = s_rate[k];
        const float om = 1.0f - rate;
        ro.x = fmaf(wr, vreg[s].x, ro.x);
        ro.y = fmaf(wr, vreg[s].y, ro.y);
        ro.z = fmaf(wr, vreg[s].z, ro.z);
        ro.w = fmaf(wr, vreg[s].w, ro.w);
        float4 kn, vn;
        kn.x = om*kreg[s].x + rate*q4.x;
        kn.y = om*kreg[s].y + rate*q4.y;
        kn.z = om*kreg[s].z + rate*q4.z;
        kn.w = om*kreg[s].w + rate*q4.w;
        vn.x = om*vreg[s].x + rate*h4.x;
        vn.y = om*vreg[s].y + rate*h4.y;
        vn.z = om*vreg[s].z + rate*h4.z;
        vn.w = om*vreg[s].w + rate*h4.w;
        ntstore4(KNb + k*Hdim + lane*4, kn);
        ntstore4(VNb + k*Hdim + lane*4, vn);
    }
    s_ro[wid][lane] = ro;
    __syncthreads();
    if (t < 64){
        float4 a = s_ro[0][t], bb = s_ro[1][t], c = s_ro[2][t], d = s_ro[3][t];
        float4 r;
        r.x = a.x+bb.x+c.x+d.x;
        r.y = a.y+bb.y+c.y+d.y;
        r.z = a.z+bb.z+c.z+d.z;
        r.w = a.w+bb.w+c.w+d.w;
        ((float4*)(ws_ro + (size_t)b*Hdim))[t] = r;
    }
}

// ---------------- Kernel C: output head (4 rows/block, 512 blocks) ----------------
__global__ __launch_bounds__(256) void kC(
    const float* __restrict__ h_t, const float* __restrict__ ws_ro,
    const float* __restrict__ u_int_prev, const int* __restrict__ step_in_macro,
    const float* __restrict__ W_mean, const float* __restrict__ b_mean,
    const float* __restrict__ W_beta, const float* __restrict__ b_beta,
    const float* __restrict__ W_sw, const float* __restrict__ b_sw,
    float* __restrict__ out_uprop, float* __restrict__ out_switch,
    float* __restrict__ out_uint, float* __restrict__ out_beta, float* __restrict__ out_swp)
{
    __shared__ float s_ctx[4][512];
    __shared__ float redb[4][4], reds[4][4];
    __shared__ float s_beff[4];
    const int t = threadIdx.x;
    const int r0 = blockIdx.x * 4;

    {
        int r = t >> 6, c4 = (t & 63) << 2;
        float4 v = *(const float4*)(h_t + (size_t)(r0+r)*Hdim + c4);
        s_ctx[r][c4+0]=v.x; s_ctx[r][c4+1]=v.y; s_ctx[r][c4+2]=v.z; s_ctx[r][c4+3]=v.w;
        v = *(const float4*)(ws_ro + (size_t)(r0+r)*Hdim + c4);
        s_ctx[r][256+c4+0]=v.x; s_ctx[r][256+c4+1]=v.y; s_ctx[r][256+c4+2]=v.z; s_ctx[r][256+c4+3]=v.w;
    }
    __syncthreads();

    const int c = t & 127;
    const int rh = t >> 7;     // 0 or 1 -> rows 2*rh, 2*rh+1
    float acc[2] = {0.f, 0.f};
    for (int i=0;i<512;i++){
        float w = W_mean[i*Udim + c];
        acc[0] = fmaf(s_ctx[2*rh+0][i], w, acc[0]);
        acc[1] = fmaf(s_ctx[2*rh+1][i], w, acc[1]);
    }

    float pb[4]={0,0,0,0}, ps[4]={0,0,0,0};
    for (int i=t; i<512; i+=256){
        float wb = W_beta[i], wsw = W_sw[i];
        #pragma unroll
        for (int r=0;r<4;r++){
            pb[r] = fmaf(s_ctx[r][i], wb, pb[r]);
            ps[r] = fmaf(s_ctx[r][i], wsw, ps[r]);
        }
    }
    const int lane = t & 63, wid = t >> 6;
    #pragma unroll
    for (int r=0;r<4;r++){
        float a = pb[r], b2 = ps[r];
        #pragma unroll
        for (int off=32; off>=1; off>>=1){
            a  += __shfl_down(a, off);
            b2 += __shfl_down(b2, off);
        }
        if (lane==0){ redb[r][wid]=a; reds[r][wid]=b2; }
    }
    __syncthreads();
    if (t < 4){
        float db  = redb[t][0]+redb[t][1]+redb[t][2]+redb[t][3] + b_beta[0];
        float dsw = reds[t][0]+reds[t][1]+reds[t][2]+reds[t][3] + b_sw[0];
        float beta = 0.05f + 0.945f*sigm(db);
        float swp = sigm(dsw);
        float swf = (swp > 0.5f) ? 1.0f : 0.0f;
        if (step_in_macro[r0+t] == 0) swf = 1.0f;
        out_beta[r0+t] = beta;
        out_swp[r0+t] = swp;
        out_switch[r0+t] = swf;
        s_beff[t] = beta*(1.0f - swf);
    }
    __syncthreads();
    #pragma unroll
    for (int j=0;j<2;j++){
        int r = 2*rh + j;
        float mean = acc[j] + b_mean[c];
        size_t o = (size_t)(r0+r)*Udim + c;
        out_uprop[o] = mean;
        float be = s_beff[r];
        out_uint[o] = be*u_int_prev[o] + (1.0f-be)*mean;
    }
}

extern "C" void kernel_launch(void* const* d_in, const int* in_sizes, int n_in,
                              void* d_out, int out_size, void* d_ws, size_t ws_size,
                              hipStream_t stream)
{
    const float* h_prev   = (const float*)d_in[0];
    const float* keys     = (const float*)d_in[1];
    const float* vals     = (const float*)d_in[2];
    const float* age      = (const float*)d_in[3];
    const float* strength = (const float*)d_in[4];
    const float* obs      = (const float*)d_in[5];
    const float* ssum     = (const float*)d_in[6];
    const float* u_int_prev = (const float*)d_in[7];
    const int*   step     = (const int*)d_in[8];
    const float* W_obs    = (const float*)d_in[9];
    const float* b_obs    = (const float*)d_in[10];
    const float* W_ssum   = (const float*)d_in[11];
    const float* b_ssum   = (const float*)d_in[12];
    const float* Wi       = (const float*)d_in[13];
    const float* bi       = (const float*)d_in[14];
    const float* Wh       = (const float*)d_in[15];
    const float* bhn      = (const float*)d_in[16];
    const float* W_gate   = (const float*)d_in[17];
    const float* b_gate   = (const float*)d_in[18];
    const float* W_mean   = (const float*)d_in[19];
    const float* b_mean   = (const float*)d_in[20];
    const float* W_beta   = (const float*)d_in[22];
    const float* b_beta   = (const float*)d_in[23];
    const float* W_sw     = (const float*)d_in[24];
    const float* b_sw     = (const float*)d_in[25];

    float* out = (float*)d_out;
    float* out_h    = out;                       // 2048*256
    float* out_kn   = out_h   + 524288;          // 2048*32*256
    float* out_vn   = out_kn  + 16777216;
    float* out_age  = out_vn  + 16777216;        // 2048*32
    float* out_str  = out_age + 65536;
    float* out_up   = out_str + 65536;           // 2048*128
    float* out_sw   = out_up  + 262144;          // 2048
    float* out_ui   = out_sw  + 2048;            // 2048*128
    float* out_beta = out_ui  + 262144;          // 2048
    float* out_swp  = out_beta+ 2048;            // 2048

    float* ws = (float*)d_ws;
    float* ws_qn   = ws;                         // B*H
    float* ws_ro   = ws + Bdim*Hdim;             // B*H
    float* ws_wstr = ws + 2*Bdim*Hdim;           // B

    // scratch reusing output regions (consumed before kB overwrites them)
    float* ws_xin = out_vn;                      // B*256 floats, overwritten by kB later
    float* ws_g   = out_kn;                      // B*1024 floats, overwritten by kB later

    kA1<<<Bdim/8, 256, 0, stream>>>(obs, ssum, W_obs, b_obs, W_ssum, b_ssum, ws_xin);
    kG2<<<512, 256, 0, stream>>>(ws_xin, h_prev, Wi, Wh, ws_g);
    kA3<<<Bdim/8, 256, 0, stream>>>(ws_g, h_prev, bi, bhn, W_gate, b_gate,
                                    out_h, ws_qn, ws_wstr);
    kB<<<Bdim, 256, 0, stream>>>(keys, vals, age, strength, out_h, ws_qn, ws_wstr,
                                 out_kn, out_vn, out_age, out_str, ws_ro);
    kC<<<Bdim/4, 256, 0, stream>>>(out_h, ws_ro, u_int_prev, step, W_mean, b_mean,
                                   W_beta, b_beta, W_sw, b_sw,
                                   out_up, out_sw, out_ui, out_beta, out_swp);
}